// Round 13
// baseline (298.423 us; speedup 1.0000x reference)
//
#include <hip/hip_runtime.h>
#include <stdint.h>

#define T_ 2048
#define C_ 2048
#define HD 128
#define LDQKV 3072

typedef unsigned short u16;
typedef __attribute__((ext_vector_type(8))) short bf16x8;   // 8 bf16 (4 VGPRs)
typedef __attribute__((ext_vector_type(4))) float f32x4;
typedef __attribute__((ext_vector_type(4))) float float4v;
typedef __attribute__((ext_vector_type(4))) u16 u16x4;
typedef __attribute__((ext_vector_type(8))) u16 u16x8;
typedef __attribute__((ext_vector_type(2))) u16 u16x2;

typedef __attribute__((address_space(3))) void lds_void;
typedef const __attribute__((address_space(1))) void gbl_void;

__device__ __forceinline__ void gload_lds16(const void* g, void* l) {
  __builtin_amdgcn_global_load_lds((gbl_void*)(uintptr_t)g,
                                   (lds_void*)(uint32_t)(uintptr_t)l, 16, 0, 0);
}

__device__ __forceinline__ u16 f2bf(float f) {
  union { float f; uint32_t u; } v; v.f = f;
  uint32_t r = v.u + 0x7FFFu + ((v.u >> 16) & 1u);
  return (u16)(r >> 16);
}
__device__ __forceinline__ float bf2f(u16 h) {
  union { uint32_t u; float f; } v; v.u = ((uint32_t)h) << 16;
  return v.f;
}

// raw barrier (NOT __syncthreads: that drains vmcnt(0) and kills the pipeline)
#define BAR() do { asm volatile("" ::: "memory"); __builtin_amdgcn_s_barrier(); asm volatile("" ::: "memory"); } while (0)
#define VMCNT(n) asm volatile("s_waitcnt vmcnt(" #n ")" ::: "memory")
// inline-asm immediates must be LITERALS (R8 lesson) -> constexpr dispatch
template<int N> __device__ __forceinline__ void VMCNT_C() {
  if constexpr (N == 0) { VMCNT(0); }
  else if constexpr (N == 3) { VMCNT(3); }
  else if constexpr (N == 4) { VMCNT(4); }
  else { static_assert(N == 0 || N == 3 || N == 4, "add literal"); }
}

// ---------- merged prep: conv_x | wt_qkv transpose | wo_t transpose | cos/sin ----------
__device__ __forceinline__ void ttile(const float* __restrict__ src, int ldw, int nb,
                                      int k0, int n0out, u16* __restrict__ out, int tid,
                                      float (*Lt)[68]) {
  int kr = tid >> 4, nc = (tid & 15) * 4;
#pragma unroll
  for (int s = 0; s < 4; ++s) {
    float4v v = *(const float4v*)(src + (size_t)(k0 + kr + 16 * s) * ldw + nb + nc);
#pragma unroll
    for (int e = 0; e < 4; ++e) Lt[kr + 16 * s][nc + e] = v[e];
  }
  __syncthreads();
  int nr = tid & 31, kc = (tid >> 5) * 8;
#pragma unroll
  for (int s2 = 0; s2 < 2; ++s2) {
    int n = nr + 32 * s2;
    u16x8 o;
#pragma unroll
    for (int e = 0; e < 8; ++e) o[e] = f2bf(Lt[kc + e][n]);
    *(u16x8*)(out + (size_t)(n0out + n) * 2048 + k0 + kc) = o;
  }
}

__global__ __launch_bounds__(256) void k_prep(const float* __restrict__ x,
                                              const float* __restrict__ Wq, const float* __restrict__ Wk,
                                              const float* __restrict__ Wv, const float* __restrict__ Wo,
                                              u16* __restrict__ xbf, u16* __restrict__ wtq,
                                              u16* __restrict__ wot, float* __restrict__ cst) {
  __shared__ float Lt[64][68];
  const int bid = blockIdx.x, tid = threadIdx.x;
  if (bid < 16384) {                                  // x -> bf16
    size_t idx = (size_t)bid * 256 + tid;
    float4v xv = *(const float4v*)(x + idx * 4);
    u16x4 r;
#pragma unroll
    for (int e = 0; e < 4; ++e) r[e] = f2bf(xv[e]);
    *(u16x4*)(xbf + idx * 4) = r;
  } else if (bid < 17920) {                           // wt_qkv: [Wq|Wk|Wv]^T
    int b = bid - 16384;
    int n0 = (b % 48) * 64, k0 = (b / 48) * 64;
    const float* src; int ldw, nb;
    if (n0 < 2048)      { src = Wq; ldw = 2048; nb = n0; }
    else if (n0 < 2560) { src = Wk; ldw = 512;  nb = n0 - 2048; }
    else                { src = Wv; ldw = 512;  nb = n0 - 2560; }
    ttile(src, ldw, nb, k0, n0, wtq, tid, Lt);
  } else if (bid < 18944) {                           // wo^T
    int b = bid - 17920;
    ttile(Wo, 2048, (b % 32) * 64, (b / 32) * 64, (b % 32) * 64, wot, tid, Lt);
  } else {                                            // cos/sin table
    int idx = (bid - 18944) * 256 + tid;              // 131072
    int t = idx >> 6, d = idx & 63;
    float inv = expf(-(float)d * (1.0f / 64.0f) * 9.2103403719761836f);
    float f = (float)t * inv;
    float s, c;
    sincosf(f, &s, &c);
    cst[idx * 2] = c;
    cst[idx * 2 + 1] = s;
  }
}

// RoPE in place, x8 vectorized; folds 1/sqrt(HD) into q heads. (HBM-roofline ~13us;
// R11 showed fusing into GEMM1 epilogue costs +32us. Keep standalone.)
__global__ __launch_bounds__(256) void k_rope(u16* __restrict__ qkv, const float* __restrict__ cst) {
  int idx = blockIdx.x * 256 + threadIdx.x;   // 1,310,720
  int token = idx / 160;
  int rem = idx - token * 160;
  int hd = rem >> 3, oct = rem & 7;
  int col = ((hd < 16) ? hd * 128 : 2048 + (hd - 16) * 128) + oct * 8;
  size_t base = (size_t)token * LDQKV + col;
  int t = token & (T_ - 1);
  float sc = (hd < 16) ? 0.08838834764831845f : 1.0f;
  u16x8 a = *(const u16x8*)(qkv + base);
  u16x8 b2 = *(const u16x8*)(qkv + base + 64);
  const float* cp = cst + (size_t)(t * 64 + oct * 8) * 2;
  u16x8 ra, rb;
#pragma unroll
  for (int e = 0; e < 8; ++e) {
    float c = cp[e * 2], s = cp[e * 2 + 1];
    float x1 = bf2f(a[e]), x2 = bf2f(b2[e]);
    ra[e] = f2bf((x1 * c - x2 * s) * sc);
    rb[e] = f2bf((x1 * s + x2 * c) * sc);
  }
  *(u16x8*)(qkv + base) = ra;
  *(u16x8*)(qkv + base + 64) = rb;
}

// ---------- 256xBN 2-phase GEMM, strength-reduced addressing (R10/R12-identical) ----------
template<int OUTF32, int NF>
__global__ __launch_bounds__(512, 1) void k_gemm8(const u16* __restrict__ A, const u16* __restrict__ Bt,
                                                  void* __restrict__ Cout, int M, int N, int K, int nbx) {
  constexpr int BUFE = 16384 + NF * 4096;   // u16 elems/buffer (A 256x64 + B NF*64x64)
  __shared__ __attribute__((aligned(16))) u16 lds[2 * BUFE];
  const int tid = threadIdx.x, lane = tid & 63;
  const int w = tid >> 6, wm = w >> 2, wn = w & 3;
  const int l15 = lane & 15, lhi = lane >> 4;
  const int nwg = gridDim.x, cpx = nwg >> 3;
  const int wg = (blockIdx.x & 7) * cpx + (blockIdx.x >> 3);
  const int bx = wg % nbx, by = wg / nbx;
  const int m0 = by * 256, n0 = bx * (NF * 64);
  const int NT = K >> 6;

  const int srow = tid >> 3;
  const int scol = ((tid & 7) ^ (srow & 7)) * 8;   // pre-swizzled global col
  const u16* pA0 = A + (size_t)(m0 + srow) * K + scol;
  const u16* pA1 = pA0 + (size_t)64 * K;
  const u16* pA2 = pA0 + (size_t)128 * K;
  const u16* pA3 = pA0 + (size_t)192 * K;
  const u16* pB0 = Bt + (size_t)(n0 + srow) * K + scol;
  const u16* pB1 = pB0 + (size_t)64 * K;
  const u16* pB2 = pB0 + (size_t)128 * K;
  const u16* pB3 = pB0 + (size_t)(NF == 4 ? 192 : 128) * K;
  u16* dEA = lds + tid * 8;
  u16* dEB = lds + 16384 + tid * 8;
  u16* dOA = lds + BUFE + tid * 8;
  u16* dOB = lds + BUFE + 16384 + tid * 8;
  const int xk0 = (lhi ^ (l15 & 7)) * 8;
  const int xk1 = ((4 + lhi) ^ (l15 & 7)) * 8;
  const u16* rAe0 = lds + (wm * 128 + l15) * 64 + xk0;
  const u16* rAe1 = lds + (wm * 128 + l15) * 64 + xk1;
  const u16* rBe0 = lds + 16384 + (wn * (NF * 16) + l15) * 64 + xk0;
  const u16* rBe1 = lds + 16384 + (wn * (NF * 16) + l15) * 64 + xk1;
  const u16* rAo0 = rAe0 + BUFE;
  const u16* rAo1 = rAe1 + BUFE;
  const u16* rBo0 = rBe0 + BUFE;
  const u16* rBo1 = rBe1 + BUFE;

  f32x4 acc[8][NF];
#pragma unroll
  for (int i = 0; i < 8; ++i)
#pragma unroll
    for (int j = 0; j < NF; ++j) acc[i][j] = (f32x4){0.f, 0.f, 0.f, 0.f};

  gload_lds16(pA0, dEA);         gload_lds16(pA1, dEA + 4096);
  gload_lds16(pA2, dEA + 8192);  gload_lds16(pA3, dEA + 12288);
  gload_lds16(pB0, dEB);         gload_lds16(pB1, dEB + 4096);
  gload_lds16(pB2, dEB + 8192);
  if constexpr (NF == 4) gload_lds16(pB3, dEB + 12288);
  pB0 += 64; pB1 += 64; pB2 += 64;
  if constexpr (NF == 4) pB3 += 64;
  gload_lds16(pB0, dOB);         gload_lds16(pB1, dOB + 4096);
  gload_lds16(pB2, dOB + 8192);
  if constexpr (NF == 4) gload_lds16(pB3, dOB + 12288);
  VMCNT_C<NF>();
  BAR();

  auto TILE = [&](const u16* rA0, const u16* rA1, const u16* rB0, const u16* rB1,
                  u16* dA, u16* dB, bool stA, bool nlast) {
    bf16x8 bb[NF][2], aa[4][2];
    auto MH = [&](int h) {   // acc rows h*4..h*4+3 x all nf, ks-outer
#pragma unroll
      for (int ks = 0; ks < 2; ++ks)
#pragma unroll
        for (int mi = 0; mi < 4; ++mi)
#pragma unroll
          for (int nf = 0; nf < NF; ++nf)
            acc[h * 4 + mi][nf] = __builtin_amdgcn_mfma_f32_16x16x32_bf16(
                aa[mi][ks], bb[nf][ks], acc[h * 4 + mi][nf], 0, 0, 0);
    };
#pragma unroll
    for (int nf = 0; nf < NF; ++nf) {
      bb[nf][0] = *(const bf16x8*)(rB0 + nf * 1024);
      bb[nf][1] = *(const bf16x8*)(rB1 + nf * 1024);
    }
#pragma unroll
    for (int mi = 0; mi < 4; ++mi) {
      aa[mi][0] = *(const bf16x8*)(rA0 + mi * 1024);
      aa[mi][1] = *(const bf16x8*)(rA1 + mi * 1024);
    }
    if (stA) {
      pA0 += 64; pA1 += 64; pA2 += 64; pA3 += 64;
      gload_lds16(pA0, dA);        gload_lds16(pA1, dA + 4096);
      gload_lds16(pA2, dA + 8192); gload_lds16(pA3, dA + 12288);
    }
    __builtin_amdgcn_s_setprio(1);
    MH(0);
    __builtin_amdgcn_s_setprio(0);
    BAR();
#pragma unroll
    for (int mi = 0; mi < 4; ++mi) {
      aa[mi][0] = *(const bf16x8*)(rA0 + 4096 + mi * 1024);
      aa[mi][1] = *(const bf16x8*)(rA1 + 4096 + mi * 1024);
    }
    if (nlast) {
      pB0 += 64; pB1 += 64; pB2 += 64;
      gload_lds16(pB0, dB);        gload_lds16(pB1, dB + 4096);
      gload_lds16(pB2, dB + 8192);
      if constexpr (NF == 4) { pB3 += 64; gload_lds16(pB3, dB + 12288); }
    }
    __builtin_amdgcn_s_setprio(1);
    MH(1);
    __builtin_amdgcn_s_setprio(0);
    if (nlast) { VMCNT_C<NF>(); } else { VMCNT_C<0>(); }
    BAR();
  };

  for (int t = 0; t < NT; t += 2) {
    const bool nlast = (t + 2 < NT);
    TILE(rAe0, rAe1, rBe0, rBe1, dOA, dEB, true,  nlast);   // tile t   (E)
    TILE(rAo0, rAo1, rBo0, rBo1, dEA, dOB, nlast, nlast);   // tile t+1 (O)
  }

#pragma unroll
  for (int mf = 0; mf < 8; ++mf) {
#pragma unroll
    for (int nf = 0; nf < NF; ++nf) {
      int col = n0 + wn * (NF * 16) + nf * 16 + l15;
#pragma unroll
      for (int r = 0; r < 4; ++r) {
        int row = m0 + wm * 128 + mf * 16 + lhi * 4 + r;
        float v = acc[mf][nf][r];
        if (OUTF32) ((float*)Cout)[(size_t)row * N + col] = v;
        else        ((u16*)Cout)[(size_t)row * N + col] = f2bf(v);
      }
    }
  }
}

// ---------- windowed flash attention: QBLK=128, 512 thr, 8 waves, per-wave tile skip ----------
// Per 128 queries: 6 K/V tiles staged (vs 10 at QBLK=64), each wave computes only its
// <=5 in-window tiles (skipped tiles are fully masked -> online-softmax state untouched).
// V-transpose staged as u16x2 pairs (8 ds_write_b32/thread, swizzle s=f(d) keeps j,j+1 adjacent).
// LDS 48KB: Ks 16K | Vt 16K | Ps 8x2K (Q-stage aliases Ks+Vt).
__global__ __launch_bounds__(512) void k_attn(const u16* __restrict__ qkv, u16* __restrict__ y) {
  const int bid = blockIdx.x;
  const int qt = bid & 15, h = (bid >> 4) & 15, b = bid >> 8;
  const int i0 = qt * 128;
  const size_t tb = (size_t)b * T_ * LDQKV;
  const u16* qb = qkv + tb + h * HD;
  const u16* kb = qkv + tb + 2048 + (h >> 2) * HD;
  const u16* vb = kb + 512;
  __shared__ __attribute__((aligned(16))) u16 smem[24576];   // 48 KB
  u16* Ks = smem;               // 64x128 (16KB), chunk-swizzled
  u16* Vt = smem + 8192;        // 128x64 (16KB), j-swizzled
  u16* Psw = smem + 16384;      // 8 waves x 16x64 (16KB), k-swizzled
  u16* Qs = smem;               // Q stage aliases Ks+Vt (32KB)
  const int tid = threadIdx.x, lane = tid & 63, w = tid >> 6;
  const int l15 = lane & 15, lhi = lane >> 4;
  u16* Ps = Psw + w * 1024;

  // stage Q [128][128], pre-swizzled source, linear LDS dest
#pragma unroll
  for (int it = 0; it < 4; ++it) {
    int c = it * 512 + tid, row = c >> 4, kc = (c & 15) ^ (row & 7);
    gload_lds16(qb + (size_t)(i0 + row) * LDQKV + kc * 8, &Qs[c * 8]);
  }
  __syncthreads();
  bf16x8 qf[4];
#pragma unroll
  for (int ks = 0; ks < 4; ++ks) {
    int row = w * 16 + l15;
    int kc = (ks * 4 + lhi) ^ (row & 7);
    qf[ks] = *(const bf16x8*)&Qs[(row * 16 + kc) * 8];
  }
  __syncthreads();   // Q region about to be overwritten by K/V staging

  f32x4 o[8];
#pragma unroll
  for (int dt = 0; dt < 8; ++dt) o[dt] = (f32x4){0.f, 0.f, 0.f, 0.f};
  float mrun[4], lrun[4];
#pragma unroll
  for (int r = 0; r < 4; ++r) { mrun[r] = -1e30f; lrun[r] = 0.f; }

  const int jb0 = (i0 >= 256) ? (i0 - 256) : 0;
  const int ntile = (i0 + 128 - jb0) >> 6;
  // wave w covers q-rows [i0+16w, i0+16w+16): in-window tiles [tlo, thi]
  const int lo_j = (i0 + 16 * w - 256 > jb0) ? (i0 + 16 * w - 256) : jb0;
  const int tlo = (lo_j - jb0) >> 6;
  const int thi = (i0 + 16 * w + 15 - jb0) >> 6;

  for (int tau = 0; tau < ntile; ++tau) {
    const int jb = jb0 + tau * 64;
    // stage K [64][128] via DMA (2 chunks/thread), pre-swizzled source
#pragma unroll
    for (int it = 0; it < 2; ++it) {
      int c = it * 512 + tid, row = c >> 4, kc = (c & 15) ^ (row & 7);
      gload_lds16(kb + (size_t)(jb + row) * LDQKV + kc * 8, &Ks[c * 8]);
    }
    // stage V transposed, paired rows -> u16x2 writes (1 iter: 512 thr x 16 elems)
    {
      int row = (tid >> 4) << 1, dc = tid & 15;
      const u16* vp = vb + (size_t)(jb + row) * LDQKV + dc * 8;
      u16x8 va = *(const u16x8*)vp;
      u16x8 vb2 = *(const u16x8*)(vp + LDQKV);
#pragma unroll
      for (int e = 0; e < 8; ++e) {
        int d = dc * 8 + e;
        int s = ((d >> 3) ^ (d & 7)) & 7;
        u16x2 pr; pr[0] = va[e]; pr[1] = vb2[e];
        *(u16x2*)&Vt[d * 64 + (row ^ (s << 3))] = pr;
      }
    }
    __syncthreads();

    if (tau >= tlo && tau <= thi) {
      // S = Q K^T (D: row=q=lhi*4+r, col=key=l15, per 16-key tile t); scale folded into q
      f32x4 s[4];
#pragma unroll
      for (int t = 0; t < 4; ++t) {
        s[t] = (f32x4){0.f, 0.f, 0.f, 0.f};
#pragma unroll
        for (int ks = 0; ks < 4; ++ks) {
          int row = t * 16 + l15;
          int kc = (ks * 4 + lhi) ^ (row & 7);
          bf16x8 kf = *(const bf16x8*)&Ks[(row * 16 + kc) * 8];
          s[t] = __builtin_amdgcn_mfma_f32_16x16x32_bf16(qf[ks], kf, s[t], 0, 0, 0);
        }
      }

      const int irow0 = i0 + w * 16 + lhi * 4;
      float rmax[4];
#pragma unroll
      for (int r = 0; r < 4; ++r) rmax[r] = -1e30f;
#pragma unroll
      for (int t = 0; t < 4; ++t) {
        int j = jb + t * 16 + l15;
#pragma unroll
        for (int r = 0; r < 4; ++r) {
          int i = irow0 + r;
          float sv = s[t][r];
          sv = (j <= i && j + 256 >= i) ? sv : -1e30f;
          s[t][r] = sv;
          rmax[r] = fmaxf(rmax[r], sv);
        }
      }
#pragma unroll
      for (int r = 0; r < 4; ++r) {
#pragma unroll
        for (int off = 1; off < 16; off <<= 1)
          rmax[r] = fmaxf(rmax[r], __shfl_xor(rmax[r], off));
      }
      float sf[4], psum[4];
#pragma unroll
      for (int r = 0; r < 4; ++r) {
        float mn = fmaxf(mrun[r], rmax[r]);
        sf[r] = __expf(mrun[r] - mn);
        mrun[r] = mn;
        psum[r] = 0.f;
      }
#pragma unroll
      for (int t = 0; t < 4; ++t) {
#pragma unroll
        for (int r = 0; r < 4; ++r) {
          float p = __expf(s[t][r] - mrun[r]);
          psum[r] += p;
          int q = lhi * 4 + r;
          int k = t * 16 + l15;
          Ps[q * 64 + (k ^ ((q & 7) << 3))] = f2bf(p);
        }
      }
#pragma unroll
      for (int r = 0; r < 4; ++r) {
#pragma unroll
        for (int off = 1; off < 16; off <<= 1)
          psum[r] += __shfl_xor(psum[r], off);
        lrun[r] = lrun[r] * sf[r] + psum[r];
      }
#pragma unroll
      for (int dt = 0; dt < 8; ++dt)
#pragma unroll
        for (int r = 0; r < 4; ++r)
          o[dt][r] = o[dt][r] * sf[r];

      bf16x8 pf[2];
#pragma unroll
      for (int ks2 = 0; ks2 < 2; ++ks2)
        pf[ks2] = *(const bf16x8*)&Ps[l15 * 64 + ((ks2 * 32 + lhi * 8) ^ ((l15 & 7) << 3))];
#pragma unroll
      for (int dt = 0; dt < 8; ++dt) {
#pragma unroll
        for (int ks2 = 0; ks2 < 2; ++ks2) {
          int d = dt * 16 + l15;
          int s2 = ((d >> 3) ^ (d & 7)) & 7;
          bf16x8 vf = *(const bf16x8*)&Vt[d * 64 + ((ks2 * 32 + lhi * 8) ^ (s2 << 3))];
          o[dt] = __builtin_amdgcn_mfma_f32_16x16x32_bf16(pf[ks2], vf, o[dt], 0, 0, 0);
        }
      }
    }
    __syncthreads();   // all reads of Ks/Vt done before next stage overwrites
  }

#pragma unroll
  for (int dt = 0; dt < 8; ++dt) {
#pragma unroll
    for (int r = 0; r < 4; ++r) {
      int i = i0 + w * 16 + lhi * 4 + r;
      float v = o[dt][r] / lrun[r];
      y[((size_t)b * T_ + i) * C_ + h * HD + dt * 16 + l15] = f2bf(v);
    }
  }
}

extern "C" void kernel_launch(void* const* d_in, const int* in_sizes, int n_in,
                              void* d_out, int out_size, void* d_ws, size_t ws_size,
                              hipStream_t stream) {
  const float* x  = (const float*)d_in[0];
  const float* Wq = (const float*)d_in[1];
  const float* Wk = (const float*)d_in[2];
  const float* Wv = (const float*)d_in[3];
  const float* Wo = (const float*)d_in[4];
  char* ws = (char*)d_ws;
  u16* x_bf   = (u16*)(ws);                 // 33,554,432 B (reused as y after GEMM1)
  u16* wt_qkv = (u16*)(ws + 33554432);      // 12,582,912 B
  u16* wo_t   = (u16*)(ws + 46137344);      //  8,388,608 B
  u16* qkv    = (u16*)(ws + 54525952);      // 50,331,648 B
  float* cst  = (float*)(ws + 104857600);   //  1,048,576 B
  u16* ybuf = x_bf;

  // merged prep: [0,16384) conv_x | [16384,17920) wt_qkv | [17920,18944) wo_t | [18944,19456) cs
  k_prep<<<19456, 256, 0, stream>>>(x, Wq, Wk, Wv, Wo, x_bf, wt_qkv, wo_t, cst);

  // GEMM1: BN=192 -> grid 512 = 2 exact rounds
  k_gemm8<0, 3><<<512, 512, 0, stream>>>(x_bf, wt_qkv, (void*)qkv, 8192, 3072, 2048, 16);

  k_rope<<<5120, 256, 0, stream>>>(qkv, cst);
  k_attn<<<1024, 512, 0, stream>>>(qkv, ybuf);   // (b:4) x (h:16) x (qt:16), QBLK=128

  // GEMM2: BN=256 -> grid 256 = 1 exact round
  k_gemm8<1, 4><<<256, 512, 0, stream>>>(ybuf, wo_t, d_out, 8192, 2048, 2048, 8);
}

// Round 14
// 285.709 us; speedup vs baseline: 1.0445x; 1.0445x over previous
//
#include <hip/hip_runtime.h>
#include <stdint.h>

#define T_ 2048
#define C_ 2048
#define HD 128
#define LDQKV 3072

typedef unsigned short u16;
typedef __attribute__((ext_vector_type(8))) short bf16x8;   // 8 bf16 (4 VGPRs)
typedef __attribute__((ext_vector_type(4))) float f32x4;
typedef __attribute__((ext_vector_type(4))) float float4v;
typedef __attribute__((ext_vector_type(4))) u16 u16x4;
typedef __attribute__((ext_vector_type(8))) u16 u16x8;
typedef __attribute__((ext_vector_type(2))) u16 u16x2;

typedef __attribute__((address_space(3))) void lds_void;
typedef const __attribute__((address_space(1))) void gbl_void;

__device__ __forceinline__ void gload_lds16(const void* g, void* l) {
  __builtin_amdgcn_global_load_lds((gbl_void*)(uintptr_t)g,
                                   (lds_void*)(uint32_t)(uintptr_t)l, 16, 0, 0);
}

__device__ __forceinline__ u16 f2bf(float f) {
  union { float f; uint32_t u; } v; v.f = f;
  uint32_t r = v.u + 0x7FFFu + ((v.u >> 16) & 1u);
  return (u16)(r >> 16);
}
__device__ __forceinline__ float bf2f(u16 h) {
  union { uint32_t u; float f; } v; v.u = ((uint32_t)h) << 16;
  return v.f;
}

// raw barrier (NOT __syncthreads: that drains vmcnt(0) and kills the pipeline)
#define BAR() do { asm volatile("" ::: "memory"); __builtin_amdgcn_s_barrier(); asm volatile("" ::: "memory"); } while (0)
#define VMCNT(n) asm volatile("s_waitcnt vmcnt(" #n ")" ::: "memory")
// inline-asm immediates must be LITERALS (R8 lesson) -> constexpr dispatch
template<int N> __device__ __forceinline__ void VMCNT_C() {
  if constexpr (N == 0) { VMCNT(0); }
  else if constexpr (N == 3) { VMCNT(3); }
  else if constexpr (N == 4) { VMCNT(4); }
  else { static_assert(N == 0 || N == 3 || N == 4, "add literal"); }
}

// ---------- merged prep: conv_x | wt_qkv transpose | wo_t transpose | cos/sin ----------
__device__ __forceinline__ void ttile(const float* __restrict__ src, int ldw, int nb,
                                      int k0, int n0out, u16* __restrict__ out, int tid,
                                      float (*Lt)[68]) {
  int kr = tid >> 4, nc = (tid & 15) * 4;
#pragma unroll
  for (int s = 0; s < 4; ++s) {
    float4v v = *(const float4v*)(src + (size_t)(k0 + kr + 16 * s) * ldw + nb + nc);
#pragma unroll
    for (int e = 0; e < 4; ++e) Lt[kr + 16 * s][nc + e] = v[e];
  }
  __syncthreads();
  int nr = tid & 31, kc = (tid >> 5) * 8;
#pragma unroll
  for (int s2 = 0; s2 < 2; ++s2) {
    int n = nr + 32 * s2;
    u16x8 o;
#pragma unroll
    for (int e = 0; e < 8; ++e) o[e] = f2bf(Lt[kc + e][n]);
    *(u16x8*)(out + (size_t)(n0out + n) * 2048 + k0 + kc) = o;
  }
}

__global__ __launch_bounds__(256) void k_prep(const float* __restrict__ x,
                                              const float* __restrict__ Wq, const float* __restrict__ Wk,
                                              const float* __restrict__ Wv, const float* __restrict__ Wo,
                                              u16* __restrict__ xbf, u16* __restrict__ wtq,
                                              u16* __restrict__ wot, float* __restrict__ cst) {
  __shared__ float Lt[64][68];
  const int bid = blockIdx.x, tid = threadIdx.x;
  if (bid < 16384) {                                  // x -> bf16
    size_t idx = (size_t)bid * 256 + tid;
    float4v xv = *(const float4v*)(x + idx * 4);
    u16x4 r;
#pragma unroll
    for (int e = 0; e < 4; ++e) r[e] = f2bf(xv[e]);
    *(u16x4*)(xbf + idx * 4) = r;
  } else if (bid < 17920) {                           // wt_qkv: [Wq|Wk|Wv]^T
    int b = bid - 16384;
    int n0 = (b % 48) * 64, k0 = (b / 48) * 64;
    const float* src; int ldw, nb;
    if (n0 < 2048)      { src = Wq; ldw = 2048; nb = n0; }
    else if (n0 < 2560) { src = Wk; ldw = 512;  nb = n0 - 2048; }
    else                { src = Wv; ldw = 512;  nb = n0 - 2560; }
    ttile(src, ldw, nb, k0, n0, wtq, tid, Lt);
  } else if (bid < 18944) {                           // wo^T
    int b = bid - 17920;
    ttile(Wo, 2048, (b % 32) * 64, (b / 32) * 64, (b % 32) * 64, wot, tid, Lt);
  } else {                                            // cos/sin table
    int idx = (bid - 18944) * 256 + tid;              // 131072
    int t = idx >> 6, d = idx & 63;
    float inv = expf(-(float)d * (1.0f / 64.0f) * 9.2103403719761836f);
    float f = (float)t * inv;
    float s, c;
    sincosf(f, &s, &c);
    cst[idx * 2] = c;
    cst[idx * 2 + 1] = s;
  }
}

// RoPE in place, x8 vectorized; folds 1/sqrt(HD) into q heads. (HBM-roofline ~13us;
// R11 showed fusing into GEMM1 epilogue costs +32us. Keep standalone.)
__global__ __launch_bounds__(256) void k_rope(u16* __restrict__ qkv, const float* __restrict__ cst) {
  int idx = blockIdx.x * 256 + threadIdx.x;   // 1,310,720
  int token = idx / 160;
  int rem = idx - token * 160;
  int hd = rem >> 3, oct = rem & 7;
  int col = ((hd < 16) ? hd * 128 : 2048 + (hd - 16) * 128) + oct * 8;
  size_t base = (size_t)token * LDQKV + col;
  int t = token & (T_ - 1);
  float sc = (hd < 16) ? 0.08838834764831845f : 1.0f;
  u16x8 a = *(const u16x8*)(qkv + base);
  u16x8 b2 = *(const u16x8*)(qkv + base + 64);
  const float* cp = cst + (size_t)(t * 64 + oct * 8) * 2;
  u16x8 ra, rb;
#pragma unroll
  for (int e = 0; e < 8; ++e) {
    float c = cp[e * 2], s = cp[e * 2 + 1];
    float x1 = bf2f(a[e]), x2 = bf2f(b2[e]);
    ra[e] = f2bf((x1 * c - x2 * s) * sc);
    rb[e] = f2bf((x1 * s + x2 * c) * sc);
  }
  *(u16x8*)(qkv + base) = ra;
  *(u16x8*)(qkv + base + 64) = rb;
}

// ---------- 256xBN 2-phase GEMM, strength-reduced addressing (R10/R12-identical) ----------
// Journal note (R12 PMC analysis): LDS data pipe is the binding resource here —
// 176 ds_read_b128 + ~56KB DMA-writes per CU per K-tile ~= 2560cyc of ~3600cyc tile
// time (71%). Wave-tiling redundancy (A read 4x, B 2x) is structural. MfmaUtil 45%.
template<int OUTF32, int NF>
__global__ __launch_bounds__(512, 1) void k_gemm8(const u16* __restrict__ A, const u16* __restrict__ Bt,
                                                  void* __restrict__ Cout, int M, int N, int K, int nbx) {
  constexpr int BUFE = 16384 + NF * 4096;   // u16 elems/buffer (A 256x64 + B NF*64x64)
  __shared__ __attribute__((aligned(16))) u16 lds[2 * BUFE];
  const int tid = threadIdx.x, lane = tid & 63;
  const int w = tid >> 6, wm = w >> 2, wn = w & 3;
  const int l15 = lane & 15, lhi = lane >> 4;
  const int nwg = gridDim.x, cpx = nwg >> 3;
  const int wg = (blockIdx.x & 7) * cpx + (blockIdx.x >> 3);
  const int bx = wg % nbx, by = wg / nbx;
  const int m0 = by * 256, n0 = bx * (NF * 64);
  const int NT = K >> 6;

  const int srow = tid >> 3;
  const int scol = ((tid & 7) ^ (srow & 7)) * 8;   // pre-swizzled global col
  const u16* pA0 = A + (size_t)(m0 + srow) * K + scol;
  const u16* pA1 = pA0 + (size_t)64 * K;
  const u16* pA2 = pA0 + (size_t)128 * K;
  const u16* pA3 = pA0 + (size_t)192 * K;
  const u16* pB0 = Bt + (size_t)(n0 + srow) * K + scol;
  const u16* pB1 = pB0 + (size_t)64 * K;
  const u16* pB2 = pB0 + (size_t)128 * K;
  const u16* pB3 = pB0 + (size_t)(NF == 4 ? 192 : 128) * K;
  u16* dEA = lds + tid * 8;
  u16* dEB = lds + 16384 + tid * 8;
  u16* dOA = lds + BUFE + tid * 8;
  u16* dOB = lds + BUFE + 16384 + tid * 8;
  const int xk0 = (lhi ^ (l15 & 7)) * 8;
  const int xk1 = ((4 + lhi) ^ (l15 & 7)) * 8;
  const u16* rAe0 = lds + (wm * 128 + l15) * 64 + xk0;
  const u16* rAe1 = lds + (wm * 128 + l15) * 64 + xk1;
  const u16* rBe0 = lds + 16384 + (wn * (NF * 16) + l15) * 64 + xk0;
  const u16* rBe1 = lds + 16384 + (wn * (NF * 16) + l15) * 64 + xk1;
  const u16* rAo0 = rAe0 + BUFE;
  const u16* rAo1 = rAe1 + BUFE;
  const u16* rBo0 = rBe0 + BUFE;
  const u16* rBo1 = rBe1 + BUFE;

  f32x4 acc[8][NF];
#pragma unroll
  for (int i = 0; i < 8; ++i)
#pragma unroll
    for (int j = 0; j < NF; ++j) acc[i][j] = (f32x4){0.f, 0.f, 0.f, 0.f};

  gload_lds16(pA0, dEA);         gload_lds16(pA1, dEA + 4096);
  gload_lds16(pA2, dEA + 8192);  gload_lds16(pA3, dEA + 12288);
  gload_lds16(pB0, dEB);         gload_lds16(pB1, dEB + 4096);
  gload_lds16(pB2, dEB + 8192);
  if constexpr (NF == 4) gload_lds16(pB3, dEB + 12288);
  pB0 += 64; pB1 += 64; pB2 += 64;
  if constexpr (NF == 4) pB3 += 64;
  gload_lds16(pB0, dOB);         gload_lds16(pB1, dOB + 4096);
  gload_lds16(pB2, dOB + 8192);
  if constexpr (NF == 4) gload_lds16(pB3, dOB + 12288);
  VMCNT_C<NF>();
  BAR();

  auto TILE = [&](const u16* rA0, const u16* rA1, const u16* rB0, const u16* rB1,
                  u16* dA, u16* dB, bool stA, bool nlast) {
    bf16x8 bb[NF][2], aa[4][2];
    auto MH = [&](int h) {   // acc rows h*4..h*4+3 x all nf, ks-outer
#pragma unroll
      for (int ks = 0; ks < 2; ++ks)
#pragma unroll
        for (int mi = 0; mi < 4; ++mi)
#pragma unroll
          for (int nf = 0; nf < NF; ++nf)
            acc[h * 4 + mi][nf] = __builtin_amdgcn_mfma_f32_16x16x32_bf16(
                aa[mi][ks], bb[nf][ks], acc[h * 4 + mi][nf], 0, 0, 0);
    };
#pragma unroll
    for (int nf = 0; nf < NF; ++nf) {
      bb[nf][0] = *(const bf16x8*)(rB0 + nf * 1024);
      bb[nf][1] = *(const bf16x8*)(rB1 + nf * 1024);
    }
#pragma unroll
    for (int mi = 0; mi < 4; ++mi) {
      aa[mi][0] = *(const bf16x8*)(rA0 + mi * 1024);
      aa[mi][1] = *(const bf16x8*)(rA1 + mi * 1024);
    }
    if (stA) {
      pA0 += 64; pA1 += 64; pA2 += 64; pA3 += 64;
      gload_lds16(pA0, dA);        gload_lds16(pA1, dA + 4096);
      gload_lds16(pA2, dA + 8192); gload_lds16(pA3, dA + 12288);
    }
    __builtin_amdgcn_s_setprio(1);
    MH(0);
    __builtin_amdgcn_s_setprio(0);
    BAR();
#pragma unroll
    for (int mi = 0; mi < 4; ++mi) {
      aa[mi][0] = *(const bf16x8*)(rA0 + 4096 + mi * 1024);
      aa[mi][1] = *(const bf16x8*)(rA1 + 4096 + mi * 1024);
    }
    if (nlast) {
      pB0 += 64; pB1 += 64; pB2 += 64;
      gload_lds16(pB0, dB);        gload_lds16(pB1, dB + 4096);
      gload_lds16(pB2, dB + 8192);
      if constexpr (NF == 4) { pB3 += 64; gload_lds16(pB3, dB + 12288); }
    }
    __builtin_amdgcn_s_setprio(1);
    MH(1);
    __builtin_amdgcn_s_setprio(0);
    if (nlast) { VMCNT_C<NF>(); } else { VMCNT_C<0>(); }
    BAR();
  };

  for (int t = 0; t < NT; t += 2) {
    const bool nlast = (t + 2 < NT);
    TILE(rAe0, rAe1, rBe0, rBe1, dOA, dEB, true,  nlast);   // tile t   (E)
    TILE(rAo0, rAo1, rBo0, rBo1, dEA, dOB, nlast, nlast);   // tile t+1 (O)
  }

#pragma unroll
  for (int mf = 0; mf < 8; ++mf) {
#pragma unroll
    for (int nf = 0; nf < NF; ++nf) {
      int col = n0 + wn * (NF * 16) + nf * 16 + l15;
#pragma unroll
      for (int r = 0; r < 4; ++r) {
        int row = m0 + wm * 128 + mf * 16 + lhi * 4 + r;
        float v = acc[mf][nf][r];
        if (OUTF32) ((float*)Cout)[(size_t)row * N + col] = v;
        else        ((u16*)Cout)[(size_t)row * N + col] = f2bf(v);
      }
    }
  }
}

// ---------- windowed flash attention (R12 geometry: QBLK=64, 256 thr, 4 blocks/CU) ----------
// R13 lesson: QBLK=128@512thr hits the VGPR 4-wave/SIMD bracket -> 2 blocks/CU, fewer
// independent barrier-groups -> regression. R12's 4x4-wave blocks (16 waves/CU, 4 sync
// domains) is the measured optimum. Only change vs R12: paired V-transpose writes
// (u16x2 -> 16 ds_write_b32/thread instead of 32 ds_write_b16).
__global__ __launch_bounds__(256) void k_attn(const u16* __restrict__ qkv, u16* __restrict__ y) {
  const int bid = blockIdx.x;
  const int qt = bid & 31, h = (bid >> 5) & 15, b = bid >> 9;
  const int i0 = qt * 64;
  const size_t tb = (size_t)b * T_ * LDQKV;
  const u16* qb = qkv + tb + h * HD;
  const u16* kb = qkv + tb + 2048 + (h >> 2) * HD;
  const u16* vb = kb + 512;
  __shared__ __attribute__((aligned(16))) u16 smem[20480];   // 40 KB
  u16* Ks = smem;
  u16* Vt = smem + 8192;
  u16* Psw = smem + 16384;
  u16* Qs = smem;
  const int tid = threadIdx.x, lane = tid & 63, w = tid >> 6;
  const int l15 = lane & 15, lhi = lane >> 4;
  u16* Ps = Psw + w * 1024;

#pragma unroll
  for (int it = 0; it < 4; ++it) {
    int c = it * 256 + tid, row = c >> 4, kc = (c & 15) ^ (row & 7);
    gload_lds16(qb + (size_t)(i0 + row) * LDQKV + kc * 8, &Qs[(it * 256 + w * 64) * 8]);
  }
  __syncthreads();
  bf16x8 qf[4];
#pragma unroll
  for (int ks = 0; ks < 4; ++ks) {
    int row = w * 16 + l15;
    int kc = (ks * 4 + lhi) ^ (row & 7);
    qf[ks] = *(const bf16x8*)&Qs[(row * 16 + kc) * 8];
  }
  __syncthreads();

  f32x4 o[8];
#pragma unroll
  for (int dt = 0; dt < 8; ++dt) o[dt] = (f32x4){0.f, 0.f, 0.f, 0.f};
  float mrun[4], lrun[4];
#pragma unroll
  for (int r = 0; r < 4; ++r) { mrun[r] = -1e30f; lrun[r] = 0.f; }

  const int jb0 = (i0 >= 256) ? (i0 - 256) : 0;
  for (int jb = jb0; jb <= i0; jb += 64) {
#pragma unroll
    for (int it = 0; it < 4; ++it) {
      int c = it * 256 + tid, row = c >> 4, kc = (c & 15) ^ (row & 7);
      gload_lds16(kb + (size_t)(jb + row) * LDQKV + kc * 8, &Ks[(it * 256 + w * 64) * 8]);
    }
    // V transposed, paired rows -> u16x2 writes (2 iters x 512 chunks)
#pragma unroll
    for (int it = 0; it < 2; ++it) {
      int c = it * 256 + tid;
      int row = (c >> 4) << 1, dc = c & 15;
      const u16* vp = vb + (size_t)(jb + row) * LDQKV + dc * 8;
      u16x8 va = *(const u16x8*)vp;
      u16x8 vb2 = *(const u16x8*)(vp + LDQKV);
#pragma unroll
      for (int e = 0; e < 8; ++e) {
        int d = dc * 8 + e;
        int s = (dc ^ e) & 7;
        u16x2 pr; pr[0] = va[e]; pr[1] = vb2[e];
        *(u16x2*)&Vt[d * 64 + (row ^ (s << 3))] = pr;
      }
    }
    __syncthreads();

    f32x4 s[4];
#pragma unroll
    for (int t = 0; t < 4; ++t) {
      s[t] = (f32x4){0.f, 0.f, 0.f, 0.f};
#pragma unroll
      for (int ks = 0; ks < 4; ++ks) {
        int row = t * 16 + l15;
        int kc = (ks * 4 + lhi) ^ (row & 7);
        bf16x8 kf = *(const bf16x8*)&Ks[(row * 16 + kc) * 8];
        s[t] = __builtin_amdgcn_mfma_f32_16x16x32_bf16(qf[ks], kf, s[t], 0, 0, 0);
      }
    }

    const int irow0 = i0 + w * 16 + lhi * 4;
    float rmax[4];
#pragma unroll
    for (int r = 0; r < 4; ++r) rmax[r] = -1e30f;
#pragma unroll
    for (int t = 0; t < 4; ++t) {
      int j = jb + t * 16 + l15;
#pragma unroll
      for (int r = 0; r < 4; ++r) {
        int i = irow0 + r;
        float sv = s[t][r];
        sv = (j <= i && j + 256 >= i) ? sv : -1e30f;
        s[t][r] = sv;
        rmax[r] = fmaxf(rmax[r], sv);
      }
    }
#pragma unroll
    for (int r = 0; r < 4; ++r) {
#pragma unroll
      for (int off = 1; off < 16; off <<= 1)
        rmax[r] = fmaxf(rmax[r], __shfl_xor(rmax[r], off));
    }
    float sf[4], psum[4];
#pragma unroll
    for (int r = 0; r < 4; ++r) {
      float mn = fmaxf(mrun[r], rmax[r]);
      sf[r] = __expf(mrun[r] - mn);
      mrun[r] = mn;
      psum[r] = 0.f;
    }
#pragma unroll
    for (int t = 0; t < 4; ++t) {
#pragma unroll
      for (int r = 0; r < 4; ++r) {
        float p = __expf(s[t][r] - mrun[r]);
        psum[r] += p;
        int q = lhi * 4 + r;
        int k = t * 16 + l15;
        Ps[q * 64 + (k ^ ((q & 7) << 3))] = f2bf(p);
      }
    }
#pragma unroll
    for (int r = 0; r < 4; ++r) {
#pragma unroll
      for (int off = 1; off < 16; off <<= 1)
        psum[r] += __shfl_xor(psum[r], off);
      lrun[r] = lrun[r] * sf[r] + psum[r];
    }
#pragma unroll
    for (int dt = 0; dt < 8; ++dt)
#pragma unroll
      for (int r = 0; r < 4; ++r)
        o[dt][r] = o[dt][r] * sf[r];

    bf16x8 pf[2];
#pragma unroll
    for (int ks2 = 0; ks2 < 2; ++ks2)
      pf[ks2] = *(const bf16x8*)&Ps[l15 * 64 + ((ks2 * 32 + lhi * 8) ^ ((l15 & 7) << 3))];
#pragma unroll
    for (int dt = 0; dt < 8; ++dt) {
#pragma unroll
      for (int ks2 = 0; ks2 < 2; ++ks2) {
        int d = dt * 16 + l15;
        int s2 = ((d >> 3) ^ (d & 7)) & 7;
        bf16x8 vf = *(const bf16x8*)&Vt[d * 64 + ((ks2 * 32 + lhi * 8) ^ (s2 << 3))];
        o[dt] = __builtin_amdgcn_mfma_f32_16x16x32_bf16(pf[ks2], vf, o[dt], 0, 0, 0);
      }
    }
    __syncthreads();
  }

#pragma unroll
  for (int dt = 0; dt < 8; ++dt) {
#pragma unroll
    for (int r = 0; r < 4; ++r) {
      int i = i0 + w * 16 + lhi * 4 + r;
      float v = o[dt][r] / lrun[r];
      y[((size_t)b * T_ + i) * C_ + h * HD + dt * 16 + l15] = f2bf(v);
    }
  }
}

extern "C" void kernel_launch(void* const* d_in, const int* in_sizes, int n_in,
                              void* d_out, int out_size, void* d_ws, size_t ws_size,
                              hipStream_t stream) {
  const float* x  = (const float*)d_in[0];
  const float* Wq = (const float*)d_in[1];
  const float* Wk = (const float*)d_in[2];
  const float* Wv = (const float*)d_in[3];
  const float* Wo = (const float*)d_in[4];
  char* ws = (char*)d_ws;
  u16* x_bf   = (u16*)(ws);                 // 33,554,432 B (reused as y after GEMM1)
  u16* wt_qkv = (u16*)(ws + 33554432);      // 12,582,912 B
  u16* wo_t   = (u16*)(ws + 46137344);      //  8,388,608 B
  u16* qkv    = (u16*)(ws + 54525952);      // 50,331,648 B
  float* cst  = (float*)(ws + 104857600);   //  1,048,576 B
  u16* ybuf = x_bf;

  // merged prep: [0,16384) conv_x | [16384,17920) wt_qkv | [17920,18944) wo_t | [18944,19456) cs
  k_prep<<<19456, 256, 0, stream>>>(x, Wq, Wk, Wv, Wo, x_bf, wt_qkv, wo_t, cst);

  // GEMM1: BN=192 -> grid 512 = 2 exact rounds
  k_gemm8<0, 3><<<512, 512, 0, stream>>>(x_bf, wt_qkv, (void*)qkv, 8192, 3072, 2048, 16);

  k_rope<<<5120, 256, 0, stream>>>(qkv, cst);
  k_attn<<<2048, 256, 0, stream>>>(qkv, ybuf);   // R12 geometry: QBLK=64, 4 blocks/CU

  // GEMM2: BN=256 -> grid 256 = 1 exact round
  k_gemm8<1, 4><<<256, 512, 0, stream>>>(ybuf, wo_t, d_out, 8192, 2048, 2048, 8);
}

// Round 16
// 284.123 us; speedup vs baseline: 1.0503x; 1.0056x over previous
//
#include <hip/hip_runtime.h>
#include <stdint.h>

#define T_ 2048
#define C_ 2048
#define HD 128
#define LDQKV 3072

typedef unsigned short u16;
typedef __attribute__((ext_vector_type(8))) short bf16x8;   // 8 bf16 (4 VGPRs)
typedef __attribute__((ext_vector_type(4))) float f32x4;
typedef __attribute__((ext_vector_type(4))) float float4v;
typedef __attribute__((ext_vector_type(4))) u16 u16x4;
typedef __attribute__((ext_vector_type(8))) u16 u16x8;
typedef __attribute__((ext_vector_type(2))) u16 u16x2;

typedef __attribute__((address_space(3))) void lds_void;
typedef const __attribute__((address_space(1))) void gbl_void;

__device__ __forceinline__ void gload_lds16(const void* g, void* l) {
  __builtin_amdgcn_global_load_lds((gbl_void*)(uintptr_t)g,
                                   (lds_void*)(uint32_t)(uintptr_t)l, 16, 0, 0);
}

__device__ __forceinline__ u16 f2bf(float f) {
  union { float f; uint32_t u; } v; v.f = f;
  uint32_t r = v.u + 0x7FFFu + ((v.u >> 16) & 1u);
  return (u16)(r >> 16);
}
__device__ __forceinline__ float bf2f(u16 h) {
  union { uint32_t u; float f; } v; v.u = ((uint32_t)h) << 16;
  return v.f;
}

// raw barrier (NOT __syncthreads: that drains vmcnt(0) and kills prefetch pipelines)
#define BAR() do { asm volatile("" ::: "memory"); __builtin_amdgcn_s_barrier(); asm volatile("" ::: "memory"); } while (0)
#define VMCNT(n) asm volatile("s_waitcnt vmcnt(" #n ")" ::: "memory")
#define LGKM0()  asm volatile("s_waitcnt lgkmcnt(0)" ::: "memory")
// inline-asm immediates must be LITERALS (R8 lesson) -> constexpr dispatch
template<int N> __device__ __forceinline__ void VMCNT_C() {
  if constexpr (N == 0) { VMCNT(0); }
  else if constexpr (N == 3) { VMCNT(3); }
  else if constexpr (N == 4) { VMCNT(4); }
  else { static_assert(N == 0 || N == 3 || N == 4, "add literal"); }
}

// ---------- merged prep: conv_x | wt_qkv transpose | wo_t transpose | cos/sin ----------
__device__ __forceinline__ void ttile(const float* __restrict__ src, int ldw, int nb,
                                      int k0, int n0out, u16* __restrict__ out, int tid,
                                      float (*Lt)[68]) {
  int kr = tid >> 4, nc = (tid & 15) * 4;
#pragma unroll
  for (int s = 0; s < 4; ++s) {
    float4v v = *(const float4v*)(src + (size_t)(k0 + kr + 16 * s) * ldw + nb + nc);
#pragma unroll
    for (int e = 0; e < 4; ++e) Lt[kr + 16 * s][nc + e] = v[e];
  }
  __syncthreads();
  int nr = tid & 31, kc = (tid >> 5) * 8;
#pragma unroll
  for (int s2 = 0; s2 < 2; ++s2) {
    int n = nr + 32 * s2;
    u16x8 o;
#pragma unroll
    for (int e = 0; e < 8; ++e) o[e] = f2bf(Lt[kc + e][n]);
    *(u16x8*)(out + (size_t)(n0out + n) * 2048 + k0 + kc) = o;
  }
}

__global__ __launch_bounds__(256) void k_prep(const float* __restrict__ x,
                                              const float* __restrict__ Wq, const float* __restrict__ Wk,
                                              const float* __restrict__ Wv, const float* __restrict__ Wo,
                                              u16* __restrict__ xbf, u16* __restrict__ wtq,
                                              u16* __restrict__ wot, float* __restrict__ cst) {
  __shared__ float Lt[64][68];
  const int bid = blockIdx.x, tid = threadIdx.x;
  if (bid < 16384) {                                  // x -> bf16
    size_t idx = (size_t)bid * 256 + tid;
    float4v xv = *(const float4v*)(x + idx * 4);
    u16x4 r;
#pragma unroll
    for (int e = 0; e < 4; ++e) r[e] = f2bf(xv[e]);
    *(u16x4*)(xbf + idx * 4) = r;
  } else if (bid < 17920) {                           // wt_qkv: [Wq|Wk|Wv]^T
    int b = bid - 16384;
    int n0 = (b % 48) * 64, k0 = (b / 48) * 64;
    const float* src; int ldw, nb;
    if (n0 < 2048)      { src = Wq; ldw = 2048; nb = n0; }
    else if (n0 < 2560) { src = Wk; ldw = 512;  nb = n0 - 2048; }
    else                { src = Wv; ldw = 512;  nb = n0 - 2560; }
    ttile(src, ldw, nb, k0, n0, wtq, tid, Lt);
  } else if (bid < 18944) {                           // wo^T
    int b = bid - 17920;
    ttile(Wo, 2048, (b % 32) * 64, (b / 32) * 64, (b % 32) * 64, wot, tid, Lt);
  } else {                                            // cos/sin table
    int idx = (bid - 18944) * 256 + tid;              // 131072
    int t = idx >> 6, d = idx & 63;
    float inv = expf(-(float)d * (1.0f / 64.0f) * 9.2103403719761836f);
    float f = (float)t * inv;
    float s, c;
    sincosf(f, &s, &c);
    cst[idx * 2] = c;
    cst[idx * 2 + 1] = s;
  }
}

// RoPE in place, x8 vectorized; folds 1/sqrt(HD) into q heads. (HBM-roofline ~13us;
// R11 showed fusing into GEMM1 epilogue costs +32us. Keep standalone.)
__global__ __launch_bounds__(256) void k_rope(u16* __restrict__ qkv, const float* __restrict__ cst) {
  int idx = blockIdx.x * 256 + threadIdx.x;   // 1,310,720
  int token = idx / 160;
  int rem = idx - token * 160;
  int hd = rem >> 3, oct = rem & 7;
  int col = ((hd < 16) ? hd * 128 : 2048 + (hd - 16) * 128) + oct * 8;
  size_t base = (size_t)token * LDQKV + col;
  int t = token & (T_ - 1);
  float sc = (hd < 16) ? 0.08838834764831845f : 1.0f;
  u16x8 a = *(const u16x8*)(qkv + base);
  u16x8 b2 = *(const u16x8*)(qkv + base + 64);
  const float* cp = cst + (size_t)(t * 64 + oct * 8) * 2;
  u16x8 ra, rb;
#pragma unroll
  for (int e = 0; e < 8; ++e) {
    float c = cp[e * 2], s = cp[e * 2 + 1];
    float x1 = bf2f(a[e]), x2 = bf2f(b2[e]);
    ra[e] = f2bf((x1 * c - x2 * s) * sc);
    rb[e] = f2bf((x1 * s + x2 * c) * sc);
  }
  *(u16x8*)(qkv + base) = ra;
  *(u16x8*)(qkv + base + 64) = rb;
}

// ---------- 256xBN 2-phase GEMM, strength-reduced addressing (R10/R12-identical) ----------
// Journal: LDS data pipe ~71% busy is the binding resource (176 ds_read_b128 + 56KB
// DMA-writes per CU-tile ~= 2560cyc of 3600cyc). MfmaUtil 45%.
template<int OUTF32, int NF>
__global__ __launch_bounds__(512, 1) void k_gemm8(const u16* __restrict__ A, const u16* __restrict__ Bt,
                                                  void* __restrict__ Cout, int M, int N, int K, int nbx) {
  constexpr int BUFE = 16384 + NF * 4096;   // u16 elems/buffer (A 256x64 + B NF*64x64)
  __shared__ __attribute__((aligned(16))) u16 lds[2 * BUFE];
  const int tid = threadIdx.x, lane = tid & 63;
  const int w = tid >> 6, wm = w >> 2, wn = w & 3;
  const int l15 = lane & 15, lhi = lane >> 4;
  const int nwg = gridDim.x, cpx = nwg >> 3;
  const int wg = (blockIdx.x & 7) * cpx + (blockIdx.x >> 3);
  const int bx = wg % nbx, by = wg / nbx;
  const int m0 = by * 256, n0 = bx * (NF * 64);
  const int NT = K >> 6;

  const int srow = tid >> 3;
  const int scol = ((tid & 7) ^ (srow & 7)) * 8;   // pre-swizzled global col
  const u16* pA0 = A + (size_t)(m0 + srow) * K + scol;
  const u16* pA1 = pA0 + (size_t)64 * K;
  const u16* pA2 = pA0 + (size_t)128 * K;
  const u16* pA3 = pA0 + (size_t)192 * K;
  const u16* pB0 = Bt + (size_t)(n0 + srow) * K + scol;
  const u16* pB1 = pB0 + (size_t)64 * K;
  const u16* pB2 = pB0 + (size_t)128 * K;
  const u16* pB3 = pB0 + (size_t)(NF == 4 ? 192 : 128) * K;
  u16* dEA = lds + tid * 8;
  u16* dEB = lds + 16384 + tid * 8;
  u16* dOA = lds + BUFE + tid * 8;
  u16* dOB = lds + BUFE + 16384 + tid * 8;
  const int xk0 = (lhi ^ (l15 & 7)) * 8;
  const int xk1 = ((4 + lhi) ^ (l15 & 7)) * 8;
  const u16* rAe0 = lds + (wm * 128 + l15) * 64 + xk0;
  const u16* rAe1 = lds + (wm * 128 + l15) * 64 + xk1;
  const u16* rBe0 = lds + 16384 + (wn * (NF * 16) + l15) * 64 + xk0;
  const u16* rBe1 = lds + 16384 + (wn * (NF * 16) + l15) * 64 + xk1;
  const u16* rAo0 = rAe0 + BUFE;
  const u16* rAo1 = rAe1 + BUFE;
  const u16* rBo0 = rBe0 + BUFE;
  const u16* rBo1 = rBe1 + BUFE;

  f32x4 acc[8][NF];
#pragma unroll
  for (int i = 0; i < 8; ++i)
#pragma unroll
    for (int j = 0; j < NF; ++j) acc[i][j] = (f32x4){0.f, 0.f, 0.f, 0.f};

  gload_lds16(pA0, dEA);         gload_lds16(pA1, dEA + 4096);
  gload_lds16(pA2, dEA + 8192);  gload_lds16(pA3, dEA + 12288);
  gload_lds16(pB0, dEB);         gload_lds16(pB1, dEB + 4096);
  gload_lds16(pB2, dEB + 8192);
  if constexpr (NF == 4) gload_lds16(pB3, dEB + 12288);
  pB0 += 64; pB1 += 64; pB2 += 64;
  if constexpr (NF == 4) pB3 += 64;
  gload_lds16(pB0, dOB);         gload_lds16(pB1, dOB + 4096);
  gload_lds16(pB2, dOB + 8192);
  if constexpr (NF == 4) gload_lds16(pB3, dOB + 12288);
  VMCNT_C<NF>();
  BAR();

  auto TILE = [&](const u16* rA0, const u16* rA1, const u16* rB0, const u16* rB1,
                  u16* dA, u16* dB, bool stA, bool nlast) {
    bf16x8 bb[NF][2], aa[4][2];
    auto MH = [&](int h) {   // acc rows h*4..h*4+3 x all nf, ks-outer
#pragma unroll
      for (int ks = 0; ks < 2; ++ks)
#pragma unroll
        for (int mi = 0; mi < 4; ++mi)
#pragma unroll
          for (int nf = 0; nf < NF; ++nf)
            acc[h * 4 + mi][nf] = __builtin_amdgcn_mfma_f32_16x16x32_bf16(
                aa[mi][ks], bb[nf][ks], acc[h * 4 + mi][nf], 0, 0, 0);
    };
#pragma unroll
    for (int nf = 0; nf < NF; ++nf) {
      bb[nf][0] = *(const bf16x8*)(rB0 + nf * 1024);
      bb[nf][1] = *(const bf16x8*)(rB1 + nf * 1024);
    }
#pragma unroll
    for (int mi = 0; mi < 4; ++mi) {
      aa[mi][0] = *(const bf16x8*)(rA0 + mi * 1024);
      aa[mi][1] = *(const bf16x8*)(rA1 + mi * 1024);
    }
    if (stA) {
      pA0 += 64; pA1 += 64; pA2 += 64; pA3 += 64;
      gload_lds16(pA0, dA);        gload_lds16(pA1, dA + 4096);
      gload_lds16(pA2, dA + 8192); gload_lds16(pA3, dA + 12288);
    }
    __builtin_amdgcn_s_setprio(1);
    MH(0);
    __builtin_amdgcn_s_setprio(0);
    BAR();
#pragma unroll
    for (int mi = 0; mi < 4; ++mi) {
      aa[mi][0] = *(const bf16x8*)(rA0 + 4096 + mi * 1024);
      aa[mi][1] = *(const bf16x8*)(rA1 + 4096 + mi * 1024);
    }
    if (nlast) {
      pB0 += 64; pB1 += 64; pB2 += 64;
      gload_lds16(pB0, dB);        gload_lds16(pB1, dB + 4096);
      gload_lds16(pB2, dB + 8192);
      if constexpr (NF == 4) { pB3 += 64; gload_lds16(pB3, dB + 12288); }
    }
    __builtin_amdgcn_s_setprio(1);
    MH(1);
    __builtin_amdgcn_s_setprio(0);
    if (nlast) { VMCNT_C<NF>(); } else { VMCNT_C<0>(); }
    BAR();
  };

  for (int t = 0; t < NT; t += 2) {
    const bool nlast = (t + 2 < NT);
    TILE(rAe0, rAe1, rBe0, rBe1, dOA, dEB, true,  nlast);   // tile t   (E)
    TILE(rAo0, rAo1, rBo0, rBo1, dEA, dOB, nlast, nlast);   // tile t+1 (O)
  }

#pragma unroll
  for (int mf = 0; mf < 8; ++mf) {
#pragma unroll
    for (int nf = 0; nf < NF; ++nf) {
      int col = n0 + wn * (NF * 16) + nf * 16 + l15;
#pragma unroll
      for (int r = 0; r < 4; ++r) {
        int row = m0 + wm * 128 + mf * 16 + lhi * 4 + r;
        float v = acc[mf][nf][r];
        if (OUTF32) ((float*)Cout)[(size_t)row * N + col] = v;
        else        ((u16*)Cout)[(size_t)row * N + col] = f2bf(v);
      }
    }
  }
}

// ---------- windowed flash attention, pipelined staging (R15 structure, R16 fix) ----------
// QBLK=64, 256 thr, 4 waves. LDS 56KB: Ks dbuf 2x16K | Vt 16K | Ps 8K -> 2 blocks/CU.
// R15 BUG FIXED: K-tile staging needs 4 iterations at 256 threads (4x256x16B = 16KB);
// R15's it<2 staged only rows 0..31 -> stale upper half -> absmax 0.467.
// Pipeline (T14): K(t+1) DMA into other Ks buffer + V(t+1) into registers, issued
// BEFORE compute(t), consumed after the next barrier. Raw s_barrier; the Vt-write's
// register dependence forces the counted vmcnt wait that drains exactly tile t's loads
// (vmcnt FIFO per m135: V-register use drains the older K-DMAs too).
__global__ __launch_bounds__(256) void k_attn(const u16* __restrict__ qkv, u16* __restrict__ y) {
  const int bid = blockIdx.x;
  const int qt = bid & 31, h = (bid >> 5) & 15, b = bid >> 9;
  const int i0 = qt * 64;
  const size_t tb = (size_t)b * T_ * LDQKV;
  const u16* qb = qkv + tb + h * HD;
  const u16* kb = qkv + tb + 2048 + (h >> 2) * HD;
  const u16* vb = kb + 512;
  __shared__ __attribute__((aligned(16))) u16 smem[28672];   // 56 KB
  u16* KsA = smem;              // K buffer 0 (8192 u16, chunk-swizzled)
  u16* KsB = smem + 8192;       // K buffer 1
  u16* Vt  = smem + 16384;      // V transposed (8192 u16, j-swizzled)
  u16* Psw = smem + 24576;      // 4 waves x 1024 u16, k-swizzled
  u16* Qs  = smem;              // Q stage aliases KsA+KsB (16KB)
  const int tid = threadIdx.x, lane = tid & 63, w = tid >> 6;
  const int l15 = lane & 15, lhi = lane >> 4;
  u16* Ps = Psw + w * 1024;

  // ---- prologue: Q stage + fragment hoist (syncthreads OK here, nothing in flight)
#pragma unroll
  for (int it = 0; it < 4; ++it) {
    int c = it * 256 + tid, row = c >> 4, kc = (c & 15) ^ (row & 7);
    gload_lds16(qb + (size_t)(i0 + row) * LDQKV + kc * 8, &Qs[c * 8]);
  }
  __syncthreads();
  bf16x8 qf[4];
#pragma unroll
  for (int ks = 0; ks < 4; ++ks) {
    int row = w * 16 + l15;
    int kc = (ks * 4 + lhi) ^ (row & 7);
    qf[ks] = *(const bf16x8*)&Qs[(row * 16 + kc) * 8];
  }
  __syncthreads();   // Q region (KsA/KsB) free for K staging

  f32x4 o[8];
#pragma unroll
  for (int dt = 0; dt < 8; ++dt) o[dt] = (f32x4){0.f, 0.f, 0.f, 0.f};
  float mrun[4], lrun[4];
#pragma unroll
  for (int r = 0; r < 4; ++r) { mrun[r] = -1e30f; lrun[r] = 0.f; }

  const int jb0 = (i0 >= 256) ? (i0 - 256) : 0;
  const int ntile = ((i0 - jb0) >> 6) + 1;

  // per-thread staging coords
  const int vrow = (tid >> 4) << 1;   // V row pair base (0..30); +32 for second pair
  const int vdc  = tid & 15;
  // issue K(0) DMA -> KsA (FULL tile: 4 x 256 chunks) ; load V(0) into regs
#pragma unroll
  for (int it = 0; it < 4; ++it) {
    int c = it * 256 + tid, row = c >> 4, kc = (c & 15) ^ (row & 7);
    gload_lds16(kb + (size_t)(jb0 + row) * LDQKV + kc * 8, &KsA[c * 8]);
  }
  u16x8 vA0, vA1, vB0, vB1;
  {
    const u16* vp = vb + (size_t)(jb0 + vrow) * LDQKV + vdc * 8;
    vA0 = *(const u16x8*)vp;
    vA1 = *(const u16x8*)(vp + LDQKV);
    const u16* vp2 = vp + (size_t)32 * LDQKV;
    vB0 = *(const u16x8*)vp2;
    vB1 = *(const u16x8*)(vp2 + LDQKV);
  }

  for (int tau = 0; tau < ntile; ++tau) {
    const int jb = jb0 + tau * 64;
    const u16* Kc = (tau & 1) ? KsB : KsA;
    u16* Kn = (tau & 1) ? KsA : KsB;
    // write Vt from regs (use of vA0.. forces counted vmcnt wait -> K(tau) also landed)
#pragma unroll
    for (int e = 0; e < 8; ++e) {
      int d = vdc * 8 + e;
      int s = (vdc ^ e) & 7;
      u16x2 p0; p0[0] = vA0[e]; p0[1] = vA1[e];
      *(u16x2*)&Vt[d * 64 + (vrow ^ (s << 3))] = p0;
      u16x2 p1; p1[0] = vB0[e]; p1[1] = vB1[e];
      *(u16x2*)&Vt[d * 64 + ((vrow + 32) ^ (s << 3))] = p1;
    }
    // prefetch next tile: K DMA into other buffer (FULL tile) + V into regs
    if (tau + 1 < ntile) {
      const int jn = jb + 64;
#pragma unroll
      for (int it = 0; it < 4; ++it) {
        int c = it * 256 + tid, row = c >> 4, kc = (c & 15) ^ (row & 7);
        gload_lds16(kb + (size_t)(jn + row) * LDQKV + kc * 8, &Kn[c * 8]);
      }
      const u16* vp = vb + (size_t)(jn + vrow) * LDQKV + vdc * 8;
      vA0 = *(const u16x8*)vp;
      vA1 = *(const u16x8*)(vp + LDQKV);
      const u16* vp2 = vp + (size_t)32 * LDQKV;
      vB0 = *(const u16x8*)vp2;
      vB1 = *(const u16x8*)(vp2 + LDQKV);
    }
    LGKM0();
    BAR();   // Vt + K(tau) globally valid; prefetches stay in flight

    // ---- compute: S = Q K^T
    f32x4 s[4];
    __builtin_amdgcn_s_setprio(1);
#pragma unroll
    for (int t = 0; t < 4; ++t) {
      s[t] = (f32x4){0.f, 0.f, 0.f, 0.f};
#pragma unroll
      for (int ks = 0; ks < 4; ++ks) {
        int row = t * 16 + l15;
        int kc = (ks * 4 + lhi) ^ (row & 7);
        bf16x8 kf = *(const bf16x8*)&Kc[(row * 16 + kc) * 8];
        s[t] = __builtin_amdgcn_mfma_f32_16x16x32_bf16(qf[ks], kf, s[t], 0, 0, 0);
      }
    }
    __builtin_amdgcn_s_setprio(0);

    const int irow0 = i0 + w * 16 + lhi * 4;
    float rmax[4];
#pragma unroll
    for (int r = 0; r < 4; ++r) rmax[r] = -1e30f;
#pragma unroll
    for (int t = 0; t < 4; ++t) {
      int j = jb + t * 16 + l15;
#pragma unroll
      for (int r = 0; r < 4; ++r) {
        int i = irow0 + r;
        float sv = s[t][r];
        sv = (j <= i && j + 256 >= i) ? sv : -1e30f;
        s[t][r] = sv;
        rmax[r] = fmaxf(rmax[r], sv);
      }
    }
#pragma unroll
    for (int r = 0; r < 4; ++r) {
#pragma unroll
      for (int off = 1; off < 16; off <<= 1)
        rmax[r] = fmaxf(rmax[r], __shfl_xor(rmax[r], off));
    }
    float sf[4], psum[4];
#pragma unroll
    for (int r = 0; r < 4; ++r) {
      float mn = fmaxf(mrun[r], rmax[r]);
      sf[r] = __expf(mrun[r] - mn);
      mrun[r] = mn;
      psum[r] = 0.f;
    }
#pragma unroll
    for (int t = 0; t < 4; ++t) {
#pragma unroll
      for (int r = 0; r < 4; ++r) {
        float p = __expf(s[t][r] - mrun[r]);
        psum[r] += p;
        int q = lhi * 4 + r;
        int k = t * 16 + l15;
        Ps[q * 64 + (k ^ ((q & 7) << 3))] = f2bf(p);
      }
    }
#pragma unroll
    for (int r = 0; r < 4; ++r) {
#pragma unroll
      for (int off = 1; off < 16; off <<= 1)
        psum[r] += __shfl_xor(psum[r], off);
      lrun[r] = lrun[r] * sf[r] + psum[r];
    }
#pragma unroll
    for (int dt = 0; dt < 8; ++dt)
#pragma unroll
      for (int r = 0; r < 4; ++r)
        o[dt][r] = o[dt][r] * sf[r];

    bf16x8 pf[2];
#pragma unroll
    for (int ks2 = 0; ks2 < 2; ++ks2)
      pf[ks2] = *(const bf16x8*)&Ps[l15 * 64 + ((ks2 * 32 + lhi * 8) ^ ((l15 & 7) << 3))];
    __builtin_amdgcn_s_setprio(1);
#pragma unroll
    for (int dt = 0; dt < 8; ++dt) {
#pragma unroll
      for (int ks2 = 0; ks2 < 2; ++ks2) {
        int d = dt * 16 + l15;
        int s2 = ((d >> 3) ^ (d & 7)) & 7;
        bf16x8 vf = *(const bf16x8*)&Vt[d * 64 + ((ks2 * 32 + lhi * 8) ^ (s2 << 3))];
        o[dt] = __builtin_amdgcn_mfma_f32_16x16x32_bf16(pf[ks2], vf, o[dt], 0, 0, 0);
      }
    }
    __builtin_amdgcn_s_setprio(0);
    BAR();   // all reads of Kc/Vt done before next tile's writes (raw: keeps prefetch)
  }

#pragma unroll
  for (int dt = 0; dt < 8; ++dt) {
#pragma unroll
    for (int r = 0; r < 4; ++r) {
      int i = i0 + w * 16 + lhi * 4 + r;
      float v = o[dt][r] / lrun[r];
      y[((size_t)b * T_ + i) * C_ + h * HD + dt * 16 + l15] = f2bf(v);
    }
  }
}

extern "C" void kernel_launch(void* const* d_in, const int* in_sizes, int n_in,
                              void* d_out, int out_size, void* d_ws, size_t ws_size,
                              hipStream_t stream) {
  const float* x  = (const float*)d_in[0];
  const float* Wq = (const float*)d_in[1];
  const float* Wk = (const float*)d_in[2];
  const float* Wv = (const float*)d_in[3];
  const float* Wo = (const float*)d_in[4];
  char* ws = (char*)d_ws;
  u16* x_bf   = (u16*)(ws);                 // 33,554,432 B (reused as y after GEMM1)
  u16* wt_qkv = (u16*)(ws + 33554432);      // 12,582,912 B
  u16* wo_t   = (u16*)(ws + 46137344);      //  8,388,608 B
  u16* qkv    = (u16*)(ws + 54525952);      // 50,331,648 B
  float* cst  = (float*)(ws + 104857600);   //  1,048,576 B
  u16* ybuf = x_bf;

  // merged prep: [0,16384) conv_x | [16384,17920) wt_qkv | [17920,18944) wo_t | [18944,19456) cs
  k_prep<<<19456, 256, 0, stream>>>(x, Wq, Wk, Wv, Wo, x_bf, wt_qkv, wo_t, cst);

  // GEMM1: BN=192 -> grid 512 = 2 exact rounds
  k_gemm8<0, 3><<<512, 512, 0, stream>>>(x_bf, wt_qkv, (void*)qkv, 8192, 3072, 2048, 16);

  k_rope<<<5120, 256, 0, stream>>>(qkv, cst);
  k_attn<<<2048, 256, 0, stream>>>(qkv, ybuf);   // QBLK=64, pipelined staging (fixed)

  // GEMM2: BN=256 -> grid 256 = 1 exact round
  k_gemm8<1, 4><<<256, 512, 0, stream>>>(ybuf, wo_t, d_out, 8192, 2048, 2048, 8);
}

// Round 17
// 282.653 us; speedup vs baseline: 1.0558x; 1.0052x over previous
//
#include <hip/hip_runtime.h>
#include <stdint.h>

#define T_ 2048
#define C_ 2048
#define HD 128
#define LDQKV 3072

typedef unsigned short u16;
typedef __attribute__((ext_vector_type(8))) short bf16x8;   // 8 bf16 (4 VGPRs)
typedef __attribute__((ext_vector_type(4))) float f32x4;
typedef __attribute__((ext_vector_type(4))) float float4v;
typedef __attribute__((ext_vector_type(4))) u16 u16x4;
typedef __attribute__((ext_vector_type(8))) u16 u16x8;
typedef __attribute__((ext_vector_type(2))) u16 u16x2;

typedef __attribute__((address_space(3))) void lds_void;
typedef const __attribute__((address_space(1))) void gbl_void;

__device__ __forceinline__ void gload_lds16(const void* g, void* l) {
  __builtin_amdgcn_global_load_lds((gbl_void*)(uintptr_t)g,
                                   (lds_void*)(uint32_t)(uintptr_t)l, 16, 0, 0);
}

__device__ __forceinline__ u16 f2bf(float f) {
  union { float f; uint32_t u; } v; v.f = f;
  uint32_t r = v.u + 0x7FFFu + ((v.u >> 16) & 1u);
  return (u16)(r >> 16);
}
__device__ __forceinline__ float bf2f(u16 h) {
  union { uint32_t u; float f; } v; v.u = ((uint32_t)h) << 16;
  return v.f;
}

// raw barrier (NOT __syncthreads: that drains vmcnt(0) and kills prefetch pipelines)
#define BAR() do { asm volatile("" ::: "memory"); __builtin_amdgcn_s_barrier(); asm volatile("" ::: "memory"); } while (0)
#define VMCNT(n) asm volatile("s_waitcnt vmcnt(" #n ")" ::: "memory")
#define LGKM0()  asm volatile("s_waitcnt lgkmcnt(0)" ::: "memory")
// inline-asm immediates must be LITERALS (R8 lesson) -> constexpr dispatch
template<int N> __device__ __forceinline__ void VMCNT_C() {
  if constexpr (N == 0) { VMCNT(0); }
  else if constexpr (N == 3) { VMCNT(3); }
  else if constexpr (N == 4) { VMCNT(4); }
  else { static_assert(N == 0 || N == 3 || N == 4, "add literal"); }
}

// ---------- merged prep: conv_x | wt_qkv transpose | wo_t transpose | cos/sin ----------
__device__ __forceinline__ void ttile(const float* __restrict__ src, int ldw, int nb,
                                      int k0, int n0out, u16* __restrict__ out, int tid,
                                      float (*Lt)[68]) {
  int kr = tid >> 4, nc = (tid & 15) * 4;
#pragma unroll
  for (int s = 0; s < 4; ++s) {
    float4v v = *(const float4v*)(src + (size_t)(k0 + kr + 16 * s) * ldw + nb + nc);
#pragma unroll
    for (int e = 0; e < 4; ++e) Lt[kr + 16 * s][nc + e] = v[e];
  }
  __syncthreads();
  int nr = tid & 31, kc = (tid >> 5) * 8;
#pragma unroll
  for (int s2 = 0; s2 < 2; ++s2) {
    int n = nr + 32 * s2;
    u16x8 o;
#pragma unroll
    for (int e = 0; e < 8; ++e) o[e] = f2bf(Lt[kc + e][n]);
    *(u16x8*)(out + (size_t)(n0out + n) * 2048 + k0 + kc) = o;
  }
}

__global__ __launch_bounds__(256) void k_prep(const float* __restrict__ x,
                                              const float* __restrict__ Wq, const float* __restrict__ Wk,
                                              const float* __restrict__ Wv, const float* __restrict__ Wo,
                                              u16* __restrict__ xbf, u16* __restrict__ wtq,
                                              u16* __restrict__ wot, float* __restrict__ cst) {
  __shared__ float Lt[64][68];
  const int bid = blockIdx.x, tid = threadIdx.x;
  if (bid < 16384) {                                  // x -> bf16
    size_t idx = (size_t)bid * 256 + tid;
    float4v xv = *(const float4v*)(x + idx * 4);
    u16x4 r;
#pragma unroll
    for (int e = 0; e < 4; ++e) r[e] = f2bf(xv[e]);
    *(u16x4*)(xbf + idx * 4) = r;
  } else if (bid < 17920) {                           // wt_qkv: [Wq|Wk|Wv]^T
    int b = bid - 16384;
    int n0 = (b % 48) * 64, k0 = (b / 48) * 64;
    const float* src; int ldw, nb;
    if (n0 < 2048)      { src = Wq; ldw = 2048; nb = n0; }
    else if (n0 < 2560) { src = Wk; ldw = 512;  nb = n0 - 2048; }
    else                { src = Wv; ldw = 512;  nb = n0 - 2560; }
    ttile(src, ldw, nb, k0, n0, wtq, tid, Lt);
  } else if (bid < 18944) {                           // wo^T
    int b = bid - 17920;
    ttile(Wo, 2048, (b % 32) * 64, (b / 32) * 64, (b % 32) * 64, wot, tid, Lt);
  } else {                                            // cos/sin table
    int idx = (bid - 18944) * 256 + tid;              // 131072
    int t = idx >> 6, d = idx & 63;
    float inv = expf(-(float)d * (1.0f / 64.0f) * 9.2103403719761836f);
    float f = (float)t * inv;
    float s, c;
    sincosf(f, &s, &c);
    cst[idx * 2] = c;
    cst[idx * 2 + 1] = s;
  }
}

// RoPE in place, x8 vectorized; folds 1/sqrt(HD) into q heads. (HBM-roofline ~13us;
// R11 showed fusing into GEMM1 epilogue costs +32us. Keep standalone.)
__global__ __launch_bounds__(256) void k_rope(u16* __restrict__ qkv, const float* __restrict__ cst) {
  int idx = blockIdx.x * 256 + threadIdx.x;   // 1,310,720
  int token = idx / 160;
  int rem = idx - token * 160;
  int hd = rem >> 3, oct = rem & 7;
  int col = ((hd < 16) ? hd * 128 : 2048 + (hd - 16) * 128) + oct * 8;
  size_t base = (size_t)token * LDQKV + col;
  int t = token & (T_ - 1);
  float sc = (hd < 16) ? 0.08838834764831845f : 1.0f;
  u16x8 a = *(const u16x8*)(qkv + base);
  u16x8 b2 = *(const u16x8*)(qkv + base + 64);
  const float* cp = cst + (size_t)(t * 64 + oct * 8) * 2;
  u16x8 ra, rb;
#pragma unroll
  for (int e = 0; e < 8; ++e) {
    float c = cp[e * 2], s = cp[e * 2 + 1];
    float x1 = bf2f(a[e]), x2 = bf2f(b2[e]);
    ra[e] = f2bf((x1 * c - x2 * s) * sc);
    rb[e] = f2bf((x1 * s + x2 * c) * sc);
  }
  *(u16x8*)(qkv + base) = ra;
  *(u16x8*)(qkv + base + 64) = rb;
}

// ---------- 256xBN 2-phase GEMM, strength-reduced addressing (R10/R12-identical) ----------
// Journal: LDS data pipe ~71% busy is the binding resource (176 ds_read_b128 + 56KB
// DMA-writes per CU-tile ~= 2560cyc of 3600cyc). MfmaUtil 45%.
template<int OUTF32, int NF>
__global__ __launch_bounds__(512, 1) void k_gemm8(const u16* __restrict__ A, const u16* __restrict__ Bt,
                                                  void* __restrict__ Cout, int M, int N, int K, int nbx) {
  constexpr int BUFE = 16384 + NF * 4096;   // u16 elems/buffer (A 256x64 + B NF*64x64)
  __shared__ __attribute__((aligned(16))) u16 lds[2 * BUFE];
  const int tid = threadIdx.x, lane = tid & 63;
  const int w = tid >> 6, wm = w >> 2, wn = w & 3;
  const int l15 = lane & 15, lhi = lane >> 4;
  const int nwg = gridDim.x, cpx = nwg >> 3;
  const int wg = (blockIdx.x & 7) * cpx + (blockIdx.x >> 3);
  const int bx = wg % nbx, by = wg / nbx;
  const int m0 = by * 256, n0 = bx * (NF * 64);
  const int NT = K >> 6;

  const int srow = tid >> 3;
  const int scol = ((tid & 7) ^ (srow & 7)) * 8;   // pre-swizzled global col
  const u16* pA0 = A + (size_t)(m0 + srow) * K + scol;
  const u16* pA1 = pA0 + (size_t)64 * K;
  const u16* pA2 = pA0 + (size_t)128 * K;
  const u16* pA3 = pA0 + (size_t)192 * K;
  const u16* pB0 = Bt + (size_t)(n0 + srow) * K + scol;
  const u16* pB1 = pB0 + (size_t)64 * K;
  const u16* pB2 = pB0 + (size_t)128 * K;
  const u16* pB3 = pB0 + (size_t)(NF == 4 ? 192 : 128) * K;
  u16* dEA = lds + tid * 8;
  u16* dEB = lds + 16384 + tid * 8;
  u16* dOA = lds + BUFE + tid * 8;
  u16* dOB = lds + BUFE + 16384 + tid * 8;
  const int xk0 = (lhi ^ (l15 & 7)) * 8;
  const int xk1 = ((4 + lhi) ^ (l15 & 7)) * 8;
  const u16* rAe0 = lds + (wm * 128 + l15) * 64 + xk0;
  const u16* rAe1 = lds + (wm * 128 + l15) * 64 + xk1;
  const u16* rBe0 = lds + 16384 + (wn * (NF * 16) + l15) * 64 + xk0;
  const u16* rBe1 = lds + 16384 + (wn * (NF * 16) + l15) * 64 + xk1;
  const u16* rAo0 = rAe0 + BUFE;
  const u16* rAo1 = rAe1 + BUFE;
  const u16* rBo0 = rBe0 + BUFE;
  const u16* rBo1 = rBe1 + BUFE;

  f32x4 acc[8][NF];
#pragma unroll
  for (int i = 0; i < 8; ++i)
#pragma unroll
    for (int j = 0; j < NF; ++j) acc[i][j] = (f32x4){0.f, 0.f, 0.f, 0.f};

  gload_lds16(pA0, dEA);         gload_lds16(pA1, dEA + 4096);
  gload_lds16(pA2, dEA + 8192);  gload_lds16(pA3, dEA + 12288);
  gload_lds16(pB0, dEB);         gload_lds16(pB1, dEB + 4096);
  gload_lds16(pB2, dEB + 8192);
  if constexpr (NF == 4) gload_lds16(pB3, dEB + 12288);
  pB0 += 64; pB1 += 64; pB2 += 64;
  if constexpr (NF == 4) pB3 += 64;
  gload_lds16(pB0, dOB);         gload_lds16(pB1, dOB + 4096);
  gload_lds16(pB2, dOB + 8192);
  if constexpr (NF == 4) gload_lds16(pB3, dOB + 12288);
  VMCNT_C<NF>();
  BAR();

  auto TILE = [&](const u16* rA0, const u16* rA1, const u16* rB0, const u16* rB1,
                  u16* dA, u16* dB, bool stA, bool nlast) {
    bf16x8 bb[NF][2], aa[4][2];
    auto MH = [&](int h) {   // acc rows h*4..h*4+3 x all nf, ks-outer
#pragma unroll
      for (int ks = 0; ks < 2; ++ks)
#pragma unroll
        for (int mi = 0; mi < 4; ++mi)
#pragma unroll
          for (int nf = 0; nf < NF; ++nf)
            acc[h * 4 + mi][nf] = __builtin_amdgcn_mfma_f32_16x16x32_bf16(
                aa[mi][ks], bb[nf][ks], acc[h * 4 + mi][nf], 0, 0, 0);
    };
#pragma unroll
    for (int nf = 0; nf < NF; ++nf) {
      bb[nf][0] = *(const bf16x8*)(rB0 + nf * 1024);
      bb[nf][1] = *(const bf16x8*)(rB1 + nf * 1024);
    }
#pragma unroll
    for (int mi = 0; mi < 4; ++mi) {
      aa[mi][0] = *(const bf16x8*)(rA0 + mi * 1024);
      aa[mi][1] = *(const bf16x8*)(rA1 + mi * 1024);
    }
    if (stA) {
      pA0 += 64; pA1 += 64; pA2 += 64; pA3 += 64;
      gload_lds16(pA0, dA);        gload_lds16(pA1, dA + 4096);
      gload_lds16(pA2, dA + 8192); gload_lds16(pA3, dA + 12288);
    }
    __builtin_amdgcn_s_setprio(1);
    MH(0);
    __builtin_amdgcn_s_setprio(0);
    BAR();
#pragma unroll
    for (int mi = 0; mi < 4; ++mi) {
      aa[mi][0] = *(const bf16x8*)(rA0 + 4096 + mi * 1024);
      aa[mi][1] = *(const bf16x8*)(rA1 + 4096 + mi * 1024);
    }
    if (nlast) {
      pB0 += 64; pB1 += 64; pB2 += 64;
      gload_lds16(pB0, dB);        gload_lds16(pB1, dB + 4096);
      gload_lds16(pB2, dB + 8192);
      if constexpr (NF == 4) { pB3 += 64; gload_lds16(pB3, dB + 12288); }
    }
    __builtin_amdgcn_s_setprio(1);
    MH(1);
    __builtin_amdgcn_s_setprio(0);
    if (nlast) { VMCNT_C<NF>(); } else { VMCNT_C<0>(); }
    BAR();
  };

  for (int t = 0; t < NT; t += 2) {
    const bool nlast = (t + 2 < NT);
    TILE(rAe0, rAe1, rBe0, rBe1, dOA, dEB, true,  nlast);   // tile t   (E)
    TILE(rAo0, rAo1, rBo0, rBo1, dEA, dOB, nlast, nlast);   // tile t+1 (O)
  }

#pragma unroll
  for (int mf = 0; mf < 8; ++mf) {
#pragma unroll
    for (int nf = 0; nf < NF; ++nf) {
      int col = n0 + wn * (NF * 16) + nf * 16 + l15;
#pragma unroll
      for (int r = 0; r < 4; ++r) {
        int row = m0 + wm * 128 + mf * 16 + lhi * 4 + r;
        float v = acc[mf][nf][r];
        if (OUTF32) ((float*)Cout)[(size_t)row * N + col] = v;
        else        ((u16*)Cout)[(size_t)row * N + col] = f2bf(v);
      }
    }
  }
}

// ---------- windowed flash attention: reg-staged K+V prefetch, 40KB LDS (R17) ----------
// QBLK=64, 256 thr, 4 waves, 4 blocks/CU (R12's measured-optimal occupancy).
// T14 without the R16 occupancy cost: K(t+1) AND V(t+1) prefetched into REGISTERS
// (issued before compute(t)); written to the single Ks/Vt buffers at start of t+1
// behind the closing barrier. Register scoreboard provides the counted vmcnt at the
// ds_write (a full compute phase after issue). VGPR budget must stay <=128 for the
// 4-waves/SIMD bracket — K regs 4xu16x8 (16) + V regs 4xu16x8 (16) over R12's ~88.
// K chunk swizzle kc=(tid&15)^((tid>>4)&7) is it-invariant (it*16 = 0 mod 8).
__global__ __launch_bounds__(256) void k_attn(const u16* __restrict__ qkv, u16* __restrict__ y) {
  const int bid = blockIdx.x;
  const int qt = bid & 31, h = (bid >> 5) & 15, b = bid >> 9;
  const int i0 = qt * 64;
  const size_t tb = (size_t)b * T_ * LDQKV;
  const u16* qb = qkv + tb + h * HD;
  const u16* kb = qkv + tb + 2048 + (h >> 2) * HD;
  const u16* vb = kb + 512;
  __shared__ __attribute__((aligned(16))) u16 smem[20480];   // 40 KB
  u16* Ks  = smem;              // 8192 u16 (16KB), chunk-swizzled
  u16* Vt  = smem + 8192;       // 8192 u16 (16KB), j-swizzled
  u16* Psw = smem + 16384;      // 4 waves x 1024 u16 (8KB), k-swizzled
  u16* Qs  = smem;              // Q stage aliases Ks+Vt (16KB)
  const int tid = threadIdx.x, lane = tid & 63, w = tid >> 6;
  const int l15 = lane & 15, lhi = lane >> 4;
  u16* Ps = Psw + w * 1024;

  // ---- prologue: Q stage + fragment hoist
#pragma unroll
  for (int it = 0; it < 4; ++it) {
    int c = it * 256 + tid, row = c >> 4, kc = (c & 15) ^ (row & 7);
    gload_lds16(qb + (size_t)(i0 + row) * LDQKV + kc * 8, &Qs[c * 8]);
  }
  __syncthreads();
  bf16x8 qf[4];
#pragma unroll
  for (int ks = 0; ks < 4; ++ks) {
    int row = w * 16 + l15;
    int kc = (ks * 4 + lhi) ^ (row & 7);
    qf[ks] = *(const bf16x8*)&Qs[(row * 16 + kc) * 8];
  }
  __syncthreads();   // Q region (Ks+Vt) free for staging

  f32x4 o[8];
#pragma unroll
  for (int dt = 0; dt < 8; ++dt) o[dt] = (f32x4){0.f, 0.f, 0.f, 0.f};
  float mrun[4], lrun[4];
#pragma unroll
  for (int r = 0; r < 4; ++r) { mrun[r] = -1e30f; lrun[r] = 0.f; }

  const int jb0 = (i0 >= 256) ? (i0 - 256) : 0;
  const int ntile = ((i0 - jb0) >> 6) + 1;

  // per-thread staging coords
  const int krow = tid >> 4;                         // K row within 16-row stripe
  const int kcs  = (tid & 15) ^ (krow & 7);          // it-invariant chunk swizzle
  const u16* kpt = kb + (size_t)(jb0 + krow) * LDQKV + kcs * 8;
  const int vrow = (tid >> 4) << 1;                  // V row pair base
  const int vdc  = tid & 15;
  const u16* vpt = vb + (size_t)(jb0 + vrow) * LDQKV + vdc * 8;

  // load tile 0 into regs: K (4 chunks) + V (2 row pairs)
  u16x8 k0 = *(const u16x8*)kpt;
  u16x8 k1 = *(const u16x8*)(kpt + (size_t)16 * LDQKV);
  u16x8 k2 = *(const u16x8*)(kpt + (size_t)32 * LDQKV);
  u16x8 k3 = *(const u16x8*)(kpt + (size_t)48 * LDQKV);
  u16x8 vA0 = *(const u16x8*)vpt;
  u16x8 vA1 = *(const u16x8*)(vpt + LDQKV);
  u16x8 vB0 = *(const u16x8*)(vpt + (size_t)32 * LDQKV);
  u16x8 vB1 = *(const u16x8*)(vpt + (size_t)32 * LDQKV + LDQKV);

  for (int tau = 0; tau < ntile; ++tau) {
    const int jb = jb0 + tau * 64;
    // ---- write staged regs -> LDS (ds_write waits on its source regs' loads: counted vmcnt)
    *(u16x8*)&Ks[tid * 8]        = k0;
    *(u16x8*)&Ks[2048 + tid * 8] = k1;
    *(u16x8*)&Ks[4096 + tid * 8] = k2;
    *(u16x8*)&Ks[6144 + tid * 8] = k3;
#pragma unroll
    for (int e = 0; e < 8; ++e) {
      int d = vdc * 8 + e;
      int s = (vdc ^ e) & 7;
      u16x2 p0; p0[0] = vA0[e]; p0[1] = vA1[e];
      *(u16x2*)&Vt[d * 64 + (vrow ^ (s << 3))] = p0;
      u16x2 p1; p1[0] = vB0[e]; p1[1] = vB1[e];
      *(u16x2*)&Vt[d * 64 + ((vrow + 32) ^ (s << 3))] = p1;
    }
    // ---- prefetch next tile into regs (flies under compute)
    if (tau + 1 < ntile) {
      const u16* kp = kpt + (size_t)(tau + 1) * 64 * LDQKV;
      k0 = *(const u16x8*)kp;
      k1 = *(const u16x8*)(kp + (size_t)16 * LDQKV);
      k2 = *(const u16x8*)(kp + (size_t)32 * LDQKV);
      k3 = *(const u16x8*)(kp + (size_t)48 * LDQKV);
      const u16* vp = vpt + (size_t)(tau + 1) * 64 * LDQKV;
      vA0 = *(const u16x8*)vp;
      vA1 = *(const u16x8*)(vp + LDQKV);
      vB0 = *(const u16x8*)(vp + (size_t)32 * LDQKV);
      vB1 = *(const u16x8*)(vp + (size_t)32 * LDQKV + LDQKV);
    }
    LGKM0();
    BAR();   // Ks/Vt globally valid; prefetch loads stay in flight

    // ---- compute: S = Q K^T
    f32x4 s[4];
    __builtin_amdgcn_s_setprio(1);
#pragma unroll
    for (int t = 0; t < 4; ++t) {
      s[t] = (f32x4){0.f, 0.f, 0.f, 0.f};
#pragma unroll
      for (int ks = 0; ks < 4; ++ks) {
        int row = t * 16 + l15;
        int kc = (ks * 4 + lhi) ^ (row & 7);
        bf16x8 kf = *(const bf16x8*)&Ks[(row * 16 + kc) * 8];
        s[t] = __builtin_amdgcn_mfma_f32_16x16x32_bf16(qf[ks], kf, s[t], 0, 0, 0);
      }
    }
    __builtin_amdgcn_s_setprio(0);

    const int irow0 = i0 + w * 16 + lhi * 4;
    float rmax[4];
#pragma unroll
    for (int r = 0; r < 4; ++r) rmax[r] = -1e30f;
#pragma unroll
    for (int t = 0; t < 4; ++t) {
      int j = jb + t * 16 + l15;
#pragma unroll
      for (int r = 0; r < 4; ++r) {
        int i = irow0 + r;
        float sv = s[t][r];
        sv = (j <= i && j + 256 >= i) ? sv : -1e30f;
        s[t][r] = sv;
        rmax[r] = fmaxf(rmax[r], sv);
      }
    }
#pragma unroll
    for (int r = 0; r < 4; ++r) {
#pragma unroll
      for (int off = 1; off < 16; off <<= 1)
        rmax[r] = fmaxf(rmax[r], __shfl_xor(rmax[r], off));
    }
    float sf[4], psum[4];
#pragma unroll
    for (int r = 0; r < 4; ++r) {
      float mn = fmaxf(mrun[r], rmax[r]);
      sf[r] = __expf(mrun[r] - mn);
      mrun[r] = mn;
      psum[r] = 0.f;
    }
#pragma unroll
    for (int t = 0; t < 4; ++t) {
#pragma unroll
      for (int r = 0; r < 4; ++r) {
        float p = __expf(s[t][r] - mrun[r]);
        psum[r] += p;
        int q = lhi * 4 + r;
        int k = t * 16 + l15;
        Ps[q * 64 + (k ^ ((q & 7) << 3))] = f2bf(p);
      }
    }
#pragma unroll
    for (int r = 0; r < 4; ++r) {
#pragma unroll
      for (int off = 1; off < 16; off <<= 1)
        psum[r] += __shfl_xor(psum[r], off);
      lrun[r] = lrun[r] * sf[r] + psum[r];
    }
#pragma unroll
    for (int dt = 0; dt < 8; ++dt)
#pragma unroll
      for (int r = 0; r < 4; ++r)
        o[dt][r] = o[dt][r] * sf[r];

    bf16x8 pf[2];
#pragma unroll
    for (int ks2 = 0; ks2 < 2; ++ks2)
      pf[ks2] = *(const bf16x8*)&Ps[l15 * 64 + ((ks2 * 32 + lhi * 8) ^ ((l15 & 7) << 3))];
    __builtin_amdgcn_s_setprio(1);
#pragma unroll
    for (int dt = 0; dt < 8; ++dt) {
#pragma unroll
      for (int ks2 = 0; ks2 < 2; ++ks2) {
        int d = dt * 16 + l15;
        int s2 = ((d >> 3) ^ (d & 7)) & 7;
        bf16x8 vf = *(const bf16x8*)&Vt[d * 64 + ((ks2 * 32 + lhi * 8) ^ (s2 << 3))];
        o[dt] = __builtin_amdgcn_mfma_f32_16x16x32_bf16(pf[ks2], vf, o[dt], 0, 0, 0);
      }
    }
    __builtin_amdgcn_s_setprio(0);
    BAR();   // all reads of Ks/Vt done before next tile's reg->LDS writes
  }

#pragma unroll
  for (int dt = 0; dt < 8; ++dt) {
#pragma unroll
    for (int r = 0; r < 4; ++r) {
      int i = i0 + w * 16 + lhi * 4 + r;
      float v = o[dt][r] / lrun[r];
      y[((size_t)b * T_ + i) * C_ + h * HD + dt * 16 + l15] = f2bf(v);
    }
  }
}

extern "C" void kernel_launch(void* const* d_in, const int* in_sizes, int n_in,
                              void* d_out, int out_size, void* d_ws, size_t ws_size,
                              hipStream_t stream) {
  const float* x  = (const float*)d_in[0];
  const float* Wq = (const float*)d_in[1];
  const float* Wk = (const float*)d_in[2];
  const float* Wv = (const float*)d_in[3];
  const float* Wo = (const float*)d_in[4];
  char* ws = (char*)d_ws;
  u16* x_bf   = (u16*)(ws);                 // 33,554,432 B (reused as y after GEMM1)
  u16* wt_qkv = (u16*)(ws + 33554432);      // 12,582,912 B
  u16* wo_t   = (u16*)(ws + 46137344);      //  8,388,608 B
  u16* qkv    = (u16*)(ws + 54525952);      // 50,331,648 B
  float* cst  = (float*)(ws + 104857600);   //  1,048,576 B
  u16* ybuf = x_bf;

  // merged prep: [0,16384) conv_x | [16384,17920) wt_qkv | [17920,18944) wo_t | [18944,19456) cs
  k_prep<<<19456, 256, 0, stream>>>(x, Wq, Wk, Wv, Wo, x_bf, wt_qkv, wo_t, cst);

  // GEMM1: BN=192 -> grid 512 = 2 exact rounds
  k_gemm8<0, 3><<<512, 512, 0, stream>>>(x_bf, wt_qkv, (void*)qkv, 8192, 3072, 2048, 16);

  k_rope<<<5120, 256, 0, stream>>>(qkv, cst);
  k_attn<<<2048, 256, 0, stream>>>(qkv, ybuf);   // reg-staged K+V prefetch, 4 blocks/CU

  // GEMM2: BN=256 -> grid 256 = 1 exact round
  k_gemm8<1, 4><<<256, 512, 0, stream>>>(ybuf, wo_t, d_out, 8192, 2048, 2048, 8);
}